// Round 1
// baseline (286.020 us; speedup 1.0000x reference)
//
#include <hip/hip_runtime.h>

typedef float f32x4 __attribute__((ext_vector_type(4)));
typedef __bf16 bf16x8 __attribute__((ext_vector_type(8)));
typedef short s16x8 __attribute__((ext_vector_type(8)));

__device__ __forceinline__ unsigned short f2bf(float f) {
  unsigned u = __builtin_bit_cast(unsigned, f);
  return (unsigned short)((u + 0x7fffu + ((u >> 16) & 1u)) >> 16);
}
__device__ __forceinline__ float bf2f(unsigned short s) {
  unsigned u = ((unsigned)s) << 16;
  return __builtin_bit_cast(float, u);
}

#define LSTR 40  // ushort row stride for LDS staging (80B: 16B-aligned, bank-spread)

// ---------------------------------------------------------------------------
// Kernel A: per-(b,n) Gram matrix G[f,g] = sum_l x[f,l]*x[g,l]
// split-K: 32 chunks of 512 pixels per (b,n); bf16 hi/lo MFMA; atomicAdd reduce
// ---------------------------------------------------------------------------
__global__ __launch_bounds__(256) void gram_kernel(const float* __restrict__ x,
                                                   float* __restrict__ G) {
  __shared__ unsigned short xsh[64 * LSTR];
  __shared__ unsigned short xsl[64 * LSTR];
  const int tid = threadIdx.x;
  const int lane = tid & 63;
  const int wave = tid >> 6;
  const int blk = blockIdx.x;
  const int chunk = blk & 31;
  const int bn = blk >> 5;
  const int b = bn >> 2;
  const int m1 = (bn >> 1) & 1;
  const int m2 = bn & 1;
  // staging mapping: thread loads 2 adjacent pixels x 4 channels
  const int px0 = (tid & 15) * 2;
  const int c0 = (tid >> 4) * 4;
  // MFMA fragment mapping
  const int mrow = lane & 15;
  const int k8 = (lane >> 4) * 8;
  const int tr0 = (wave >> 1) * 2;  // row-tile pair
  const int tc0 = (wave & 1) * 2;   // col-tile pair

  f32x4 acc[2][2];
#pragma unroll
  for (int i = 0; i < 2; ++i)
#pragma unroll
    for (int j = 0; j < 2; ++j) acc[i][j] = (f32x4){0.f, 0.f, 0.f, 0.f};

  for (int ks = 0; ks < 16; ++ks) {
    int l0 = chunk * 512 + ks * 32 + px0;  // pixel index within (b,n)
    int hy = l0 >> 7, wx = l0 & 127;
    int y = 2 * hy + m1, xx = 2 * wx + m2;
    const float* p0 = x + ((b * 256 + y) * 256 + xx) * 64 + c0;
    f32x4 v0 = *(const f32x4*)p0;
    f32x4 v1 = *(const f32x4*)(p0 + 128);  // next pixel in wx (+2 in xx)
    __syncthreads();
#pragma unroll
    for (int i = 0; i < 4; ++i) {
      unsigned short h0 = f2bf(v0[i]), h1 = f2bf(v1[i]);
      unsigned short g0 = f2bf(v0[i] - bf2f(h0)), g1 = f2bf(v1[i] - bf2f(h1));
      *(unsigned*)&xsh[(c0 + i) * LSTR + px0] = (unsigned)h0 | ((unsigned)h1 << 16);
      *(unsigned*)&xsl[(c0 + i) * LSTR + px0] = (unsigned)g0 | ((unsigned)g1 << 16);
    }
    __syncthreads();
    s16x8 rh[2], rl[2], qh[2], ql[2];
#pragma unroll
    for (int i = 0; i < 2; ++i) {
      rh[i] = *(const s16x8*)&xsh[(16 * (tr0 + i) + mrow) * LSTR + k8];
      rl[i] = *(const s16x8*)&xsl[(16 * (tr0 + i) + mrow) * LSTR + k8];
      qh[i] = *(const s16x8*)&xsh[(16 * (tc0 + i) + mrow) * LSTR + k8];
      ql[i] = *(const s16x8*)&xsl[(16 * (tc0 + i) + mrow) * LSTR + k8];
    }
#pragma unroll
    for (int i = 0; i < 2; ++i)
#pragma unroll
      for (int j = 0; j < 2; ++j) {
        bf16x8 ah = __builtin_bit_cast(bf16x8, rh[i]);
        bf16x8 al = __builtin_bit_cast(bf16x8, rl[i]);
        bf16x8 bh = __builtin_bit_cast(bf16x8, qh[j]);
        bf16x8 bl = __builtin_bit_cast(bf16x8, ql[j]);
        acc[i][j] = __builtin_amdgcn_mfma_f32_16x16x32_bf16(ah, bh, acc[i][j], 0, 0, 0);
        acc[i][j] = __builtin_amdgcn_mfma_f32_16x16x32_bf16(ah, bl, acc[i][j], 0, 0, 0);
        acc[i][j] = __builtin_amdgcn_mfma_f32_16x16x32_bf16(al, bh, acc[i][j], 0, 0, 0);
      }
  }
  float* Gp = G + bn * 4096;
#pragma unroll
  for (int i = 0; i < 2; ++i)
#pragma unroll
    for (int j = 0; j < 2; ++j)
#pragma unroll
      for (int r = 0; r < 4; ++r) {
        int row = 16 * (tr0 + i) + (lane >> 4) * 4 + r;
        int col = 16 * (tc0 + j) + (lane & 15);
        atomicAdd(&Gp[row * 64 + col], acc[i][j][r]);
      }
}

// ---------------------------------------------------------------------------
// Kernel B: per (b,n): S = temp*Wq^T G Wk; W=softmax(S); F = Wv (W^T Wproj)
// all fp32 in LDS; 32 workgroups
// ---------------------------------------------------------------------------
__device__ __forceinline__ void mm64(const float* Ab, int ars, int acs,
                                     const float* Bb, float* Dst, int ds,
                                     float scale, int ti4, int tj4) {
  float acc[4][4] = {};
  for (int kk = 0; kk < 64; ++kk) {
    float av[4];
#pragma unroll
    for (int i = 0; i < 4; ++i) av[i] = Ab[(ti4 + i) * ars + kk * acs];
#pragma unroll
    for (int j = 0; j < 4; ++j) {
      float bv = Bb[kk * 68 + tj4 + j];
#pragma unroll
      for (int i = 0; i < 4; ++i) acc[i][j] += av[i] * bv;
    }
  }
#pragma unroll
  for (int i = 0; i < 4; ++i)
#pragma unroll
    for (int j = 0; j < 4; ++j) Dst[(ti4 + i) * ds + tj4 + j] = scale * acc[i][j];
}

__global__ __launch_bounds__(256) void fuse_kernel(const float* __restrict__ G,
                                                   const float* __restrict__ Wqkv,
                                                   const float* __restrict__ Wproj,
                                                   float* __restrict__ F) {
  __shared__ float A[64 * 68];
  __shared__ float B[64 * 68];
  __shared__ float T[64 * 68];
  const int tid = threadIdx.x;
  const int bn = blockIdx.x;
  const int ti4 = (tid >> 4) * 4, tj4 = (tid & 15) * 4;

  // load G -> A, Wk -> B
  for (int i = tid; i < 4096; i += 256) {
    int r = i >> 6, c = i & 63;
    A[r * 68 + c] = G[bn * 4096 + i];
    B[r * 68 + c] = Wqkv[r * 192 + 64 + c];
  }
  __syncthreads();
  // T1[f][d] = sum_g G[f][g] Wk[g][d]
  mm64(A, 68, 1, B, T, 68, 1.f, ti4, tj4);
  __syncthreads();
  // Wq -> B
  for (int i = tid; i < 4096; i += 256) {
    int r = i >> 6, c = i & 63;
    B[r * 68 + c] = Wqkv[r * 192 + c];
  }
  __syncthreads();
  // S[c][d] = temp * sum_f Wq[f][c] T1[f][d]   -> A
  mm64(B, 1, 68, T, A, 68, 0.125f, ti4, tj4);
  __syncthreads();
  // softmax rows of A (over d)
  if (tid < 64) {
    float mx = -1e30f;
    for (int d = 0; d < 64; ++d) mx = fmaxf(mx, A[tid * 68 + d]);
    float s = 0.f;
    for (int d = 0; d < 64; ++d) {
      float e = __expf(A[tid * 68 + d] - mx);
      A[tid * 68 + d] = e;
      s += e;
    }
    float inv = 1.f / s;
    for (int d = 0; d < 64; ++d) A[tid * 68 + d] *= inv;
  }
  __syncthreads();
  // Wproj -> B
  for (int i = tid; i < 4096; i += 256) {
    int r = i >> 6, c = i & 63;
    B[r * 68 + c] = Wproj[i];
  }
  __syncthreads();
  // T2[d][e] = sum_c W[c][d] Wproj[c][e]   -> T
  mm64(A, 1, 68, B, T, 68, 1.f, ti4, tj4);
  __syncthreads();
  // Wv -> B
  for (int i = tid; i < 4096; i += 256) {
    int r = i >> 6, c = i & 63;
    B[r * 68 + c] = Wqkv[r * 192 + 128 + c];
  }
  __syncthreads();
  // F[f][e] = sum_d Wv[f][d] T2[d][e]  -> global
  mm64(B, 68, 1, T, F + bn * 4096, 64, 1.f, ti4, tj4);
}

// ---------------------------------------------------------------------------
// Kernel C: out[pixel][e] = sum_f x[pixel][f] * F[bn(pixel)][f][e]
// bf16 hi/lo MFMA, A-frags straight from global (no LDS), B-frags in regs
// grid: (b,n,hy-pair) = 8*4*64; each WG does 2 rows x 128 wx = 256 pixels
// ---------------------------------------------------------------------------
__global__ __launch_bounds__(256) void out_kernel(const float* __restrict__ x,
                                                  const float* __restrict__ F,
                                                  float* __restrict__ out) {
  const int tid = threadIdx.x;
  const int lane = tid & 63;
  const int wave = tid >> 6;
  const int blk = blockIdx.x;
  const int hyg = blk & 63;
  const int bn = blk >> 6;
  const int b = bn >> 2;
  const int m1 = (bn >> 1) & 1;
  const int m2 = bn & 1;

  // B-frags (Wfused), hi/lo
  s16x8 bh[2][4], bl[2][4];
  const float* Fp = F + bn * 4096;
#pragma unroll
  for (int ksj = 0; ksj < 2; ++ksj)
#pragma unroll
    for (int tc = 0; tc < 4; ++tc) {
      s16x8 hv, lv;
#pragma unroll
      for (int j = 0; j < 8; ++j) {
        int k = ksj * 32 + (lane >> 4) * 8 + j;
        int e = tc * 16 + (lane & 15);
        float f = Fp[k * 64 + e];
        unsigned short hb = f2bf(f);
        hv[j] = (short)hb;
        lv[j] = (short)f2bf(f - bf2f(hb));
      }
      bh[ksj][tc] = hv;
      bl[ksj][tc] = lv;
    }

  for (int r = 0; r < 2; ++r) {
    int hy = hyg * 2 + r;
    int y = 2 * hy + m1;
    const float* xrow = x + ((b * 256 + y) * 256) * 64;
    float* orow = out + ((b * 256 + y) * 256) * 64;
#pragma unroll
    for (int ptI = 0; ptI < 2; ++ptI) {
      int pt = wave + ptI * 4;  // px-tile 0..7
      int wx = pt * 16 + (lane & 15);
      int xx = 2 * wx + m2;
      const float* pp = xrow + xx * 64 + (lane >> 4) * 8;
      s16x8 ah[2], al[2];
#pragma unroll
      for (int ksj = 0; ksj < 2; ++ksj) {
        f32x4 u0 = *(const f32x4*)(pp + ksj * 32);
        f32x4 u1 = *(const f32x4*)(pp + ksj * 32 + 4);
        s16x8 hv, lv;
#pragma unroll
        for (int j = 0; j < 4; ++j) {
          unsigned short hb0 = f2bf(u0[j]);
          unsigned short hb1 = f2bf(u1[j]);
          hv[j] = (short)hb0;
          hv[4 + j] = (short)hb1;
          lv[j] = (short)f2bf(u0[j] - bf2f(hb0));
          lv[4 + j] = (short)f2bf(u1[j] - bf2f(hb1));
        }
        ah[ksj] = hv;
        al[ksj] = lv;
      }
      f32x4 acc[4];
#pragma unroll
      for (int tc = 0; tc < 4; ++tc) acc[tc] = (f32x4){0.f, 0.f, 0.f, 0.f};
#pragma unroll
      for (int ksj = 0; ksj < 2; ++ksj)
#pragma unroll
        for (int tc = 0; tc < 4; ++tc) {
          bf16x8 A_h = __builtin_bit_cast(bf16x8, ah[ksj]);
          bf16x8 A_l = __builtin_bit_cast(bf16x8, al[ksj]);
          bf16x8 B_h = __builtin_bit_cast(bf16x8, bh[ksj][tc]);
          bf16x8 B_l = __builtin_bit_cast(bf16x8, bl[ksj][tc]);
          acc[tc] = __builtin_amdgcn_mfma_f32_16x16x32_bf16(A_h, B_h, acc[tc], 0, 0, 0);
          acc[tc] = __builtin_amdgcn_mfma_f32_16x16x32_bf16(A_h, B_l, acc[tc], 0, 0, 0);
          acc[tc] = __builtin_amdgcn_mfma_f32_16x16x32_bf16(A_l, B_h, acc[tc], 0, 0, 0);
        }
#pragma unroll
      for (int tc = 0; tc < 4; ++tc)
#pragma unroll
        for (int j = 0; j < 4; ++j) {
          int prow = (lane >> 4) * 4 + j;
          int xx2 = 2 * (pt * 16 + prow) + m2;
          orow[xx2 * 64 + tc * 16 + (lane & 15)] = acc[tc][j];
        }
    }
  }
}

extern "C" void kernel_launch(void* const* d_in, const int* in_sizes, int n_in,
                              void* d_out, int out_size, void* d_ws, size_t ws_size,
                              hipStream_t stream) {
  (void)in_sizes; (void)n_in; (void)out_size; (void)ws_size;
  const float* x = (const float*)d_in[0];
  const float* Wqkv = (const float*)d_in[1];
  const float* Wproj = (const float*)d_in[2];
  float* out = (float*)d_out;
  float* G = (float*)d_ws;            // 32*4096 floats = 512 KB
  float* F = G + 32 * 4096;           // 32*4096 floats = 512 KB

  hipMemsetAsync(G, 0, 32 * 4096 * sizeof(float), stream);
  gram_kernel<<<1024, 256, 0, stream>>>(x, G);
  fuse_kernel<<<32, 256, 0, stream>>>(G, Wqkv, Wproj, F);
  out_kernel<<<2048, 256, 0, stream>>>(x, F, out);
}